// Round 3
// baseline (463.024 us; speedup 1.0000x reference)
//
#include <hip/hip_runtime.h>

#define NN 50000
#define NE 800000
#define D 128
#define NEG 0.2f
#define NBKT 3125        // 50000 / 16 nodes per bucket
#define KP 136           // padded LDS k-stride (bf16 elems)

typedef short bf8_t __attribute__((ext_vector_type(8)));   // 8 x bf16 (16 B)
typedef float f4_t __attribute__((ext_vector_type(4)));

__device__ __forceinline__ unsigned short f2bf(float f) {
  unsigned int u = __float_as_uint(f);
  unsigned int r = (u + 0x7FFF + ((u >> 16) & 1)) >> 16;  // RNE
  return (unsigned short)r;
}
__device__ __forceinline__ float bf2f(unsigned int bits16) {
  return __uint_as_float(bits16 << 16);
}

// ---------------- weight prep: fp32 W[k][n] -> bf16 WT[n][k], 9 matrices ----------------
__global__ __launch_bounds__(256) void prep_weights(
    const float* __restrict__ Wq, const float* __restrict__ Wk,
    const float* __restrict__ Wr, const float* __restrict__ Wro,
    unsigned short* __restrict__ WT) {
  const int m = blockIdx.y;
  const float* src;
  if (m < 2) src = Wq + m * D * D;
  else if (m < 4) src = Wk + (m - 2) * D * D;
  else if (m < 6) src = Wr + (m - 4) * D * D;
  else src = Wro + (m - 6) * D * D;
  unsigned short* dstp = WT + m * D * D;
  const int t = threadIdx.x;
  const int n = blockIdx.x * 2 + (t >> 7);
  const int k = t & 127;
  dstp[n * D + k] = f2bf(src[k * D + n]);
}

__global__ __launch_bounds__(256) void convert_feats(const float* __restrict__ in,
                                                     unsigned short* __restrict__ out) {
  int i = (blockIdx.x * 256 + threadIdx.x) * 4;
  float4 v = *(const float4*)(in + i);
  ushort4 o = {f2bf(v.x), f2bf(v.y), f2bf(v.z), f2bf(v.w)};
  *(ushort4*)(out + i) = o;
}

// ---------------- bucketed CSR build ----------------
__global__ void bucket_hist(const int* __restrict__ dst, int* __restrict__ bcnt) {
  int e = blockIdx.x * 256 + threadIdx.x;
  if (e < NE) atomicAdd(&bcnt[dst[e] >> 4], 1);
}

__global__ __launch_bounds__(1024) void bucket_scan(const int* __restrict__ bcnt,
                                                    int* __restrict__ bptr) {
  __shared__ int sd[1024];
  const int t = threadIdx.x;
  int carry = 0;
  for (int base = 0; base < NBKT; base += 1024) {
    int i = base + t;
    int x = (i < NBKT) ? bcnt[i] : 0;
    int acc = x;
    sd[t] = acc;
    __syncthreads();
    for (int off = 1; off < 1024; off <<= 1) {
      int y = (t >= off) ? sd[t - off] : 0;
      __syncthreads();
      acc += y;
      sd[t] = acc;
      __syncthreads();
    }
    if (i < NBKT) bptr[i] = carry + acc - x;   // exclusive
    carry += sd[1023];
    __syncthreads();
  }
  if (t == 0) bptr[NBKT] = carry;
}

// append-ordered scatter of packed edges: src(16b) | local_dst(4b)<<16
__global__ void bucket_scatter(const int* __restrict__ src, const int* __restrict__ dst,
                               const int* __restrict__ bptr, int* __restrict__ bfill,
                               int* __restrict__ ebuf) {
  int e = blockIdx.x * 256 + threadIdx.x;
  if (e < NE) {
    int d = dst[e];
    int b = d >> 4;
    int pos = bptr[b] + atomicAdd(&bfill[b], 1);
    ebuf[pos] = src[e] | ((d & 15) << 16);
  }
}

// per-bucket counting sort -> ssrc (dst-grouped), per-node rowptr + deg
__global__ __launch_bounds__(256) void bucket_sort(const int* __restrict__ bptr,
                                                   const int* __restrict__ ebuf,
                                                   int* __restrict__ ssrc,
                                                   int* __restrict__ rowptr,
                                                   int* __restrict__ deg) {
  __shared__ int lcnt[16], lofs[16], lfill[16];
  const int b = blockIdx.x;
  const int t = threadIdx.x;
  const int v0 = b << 4;
  const int beg = bptr[b];
  const int end = bptr[b + 1];
  if (t < 16) lcnt[t] = 0;
  __syncthreads();
  for (int i = beg + t; i < end; i += 256)
    atomicAdd(&lcnt[(ebuf[i] >> 16) & 15], 1);
  __syncthreads();
  if (t == 0) {
    int run = 0;
#pragma unroll
    for (int j = 0; j < 16; ++j) { lofs[j] = run; lfill[j] = run; run += lcnt[j]; }
  }
  __syncthreads();
  if (t < 16) {
    rowptr[v0 + t] = beg + lofs[t];
    deg[v0 + t] = lcnt[t];
  }
  for (int i = beg + t; i < end; i += 256) {
    int p = ebuf[i];
    int pos = beg + atomicAdd(&lfill[(p >> 16) & 15], 1);
    ssrc[pos] = p & 0xFFFF;
  }
  if (b == 0 && t == 0) rowptr[NN] = NE;
}

// ---------------- aggregation: agg[v] = mean_e leaky(hq[v] + hk[src[e]]) ----------------
__global__ __launch_bounds__(256) void aggregate_kernel(
    const int* __restrict__ rowptr, const int* __restrict__ ssrc,
    const unsigned short* __restrict__ hq, const unsigned short* __restrict__ hk,
    const int* __restrict__ deg, unsigned short* __restrict__ agg) {
  const int v = blockIdx.x * 4 + (threadIdx.x >> 6);
  if (v >= NN) return;
  const int lane = threadIdx.x & 63;
  const int beg = rowptr[v];
  const int end = rowptr[v + 1];
  unsigned int qb = *(const unsigned int*)(hq + (size_t)v * D + lane * 2);
  const float q0 = bf2f(qb & 0xFFFFu);
  const float q1 = bf2f(qb >> 16);
  float a0 = 0.f, a1 = 0.f;
  int e = beg;
  for (; e + 4 <= end; e += 4) {
    int s0 = ssrc[e], s1 = ssrc[e + 1], s2 = ssrc[e + 2], s3 = ssrc[e + 3];
    unsigned int k0 = *(const unsigned int*)(hk + (size_t)s0 * D + lane * 2);
    unsigned int k1 = *(const unsigned int*)(hk + (size_t)s1 * D + lane * 2);
    unsigned int k2 = *(const unsigned int*)(hk + (size_t)s2 * D + lane * 2);
    unsigned int k3 = *(const unsigned int*)(hk + (size_t)s3 * D + lane * 2);
    float m;
    m = q0 + bf2f(k0 & 0xFFFFu); a0 += (m >= 0.f) ? m : NEG * m;
    m = q1 + bf2f(k0 >> 16);     a1 += (m >= 0.f) ? m : NEG * m;
    m = q0 + bf2f(k1 & 0xFFFFu); a0 += (m >= 0.f) ? m : NEG * m;
    m = q1 + bf2f(k1 >> 16);     a1 += (m >= 0.f) ? m : NEG * m;
    m = q0 + bf2f(k2 & 0xFFFFu); a0 += (m >= 0.f) ? m : NEG * m;
    m = q1 + bf2f(k2 >> 16);     a1 += (m >= 0.f) ? m : NEG * m;
    m = q0 + bf2f(k3 & 0xFFFFu); a0 += (m >= 0.f) ? m : NEG * m;
    m = q1 + bf2f(k3 >> 16);     a1 += (m >= 0.f) ? m : NEG * m;
  }
  for (; e < end; ++e) {
    int s = ssrc[e];
    unsigned int kb = *(const unsigned int*)(hk + (size_t)s * D + lane * 2);
    float m;
    m = q0 + bf2f(kb & 0xFFFFu); a0 += (m >= 0.f) ? m : NEG * m;
    m = q1 + bf2f(kb >> 16);     a1 += (m >= 0.f) ? m : NEG * m;
  }
  float dnm = fmaxf((float)deg[v], 1.f);
  unsigned int ob = (unsigned int)f2bf(a0 / dnm) | ((unsigned int)f2bf(a1 / dnm) << 16);
  *(unsigned int*)(agg + (size_t)v * D + lane * 2) = ob;
}

// ---------------- single-output MFMA GEMM (r-gemm: leaky, bf16 out) ----------------
__global__ __launch_bounds__(256) void gemm_r(const unsigned short* __restrict__ A,
                                              const unsigned short* __restrict__ WT,
                                              const float* __restrict__ bias,
                                              unsigned short* __restrict__ C, int M) {
  __shared__ unsigned short w[D * KP];
  const int t = threadIdx.x;
#pragma unroll
  for (int i = 0; i < 8; ++i) {
    int idx8 = t + i * 256;
    int n = idx8 >> 4, k8 = (idx8 & 15) << 3;
    *(uint4*)(&w[n * KP + k8]) = *(const uint4*)(&WT[n * D + k8]);
  }
  __syncthreads();

  const int wave = t >> 6;
  const int lane = t & 63;
  const int l15 = lane & 15;
  const int quad = lane >> 4;
  const int row_base = blockIdx.x * 128 + wave * 32;

  int r0 = row_base + l15;      if (r0 >= M) r0 = M - 1;
  int r1 = row_base + 16 + l15; if (r1 >= M) r1 = M - 1;
  const unsigned short* A0 = A + (size_t)r0 * D + quad * 8;
  const unsigned short* A1 = A + (size_t)r1 * D + quad * 8;

  f4_t acc[2][8] = {};
#pragma unroll
  for (int kc = 0; kc < 4; ++kc) {
    bf8_t a0 = *(const bf8_t*)(A0 + kc * 32);
    bf8_t a1 = *(const bf8_t*)(A1 + kc * 32);
#pragma unroll
    for (int nt = 0; nt < 8; ++nt) {
      bf8_t b = *(const bf8_t*)(&w[(nt * 16 + l15) * KP + kc * 32 + quad * 8]);
      acc[0][nt] = __builtin_amdgcn_mfma_f32_16x16x32_bf16(a0, b, acc[0][nt], 0, 0, 0);
      acc[1][nt] = __builtin_amdgcn_mfma_f32_16x16x32_bf16(a1, b, acc[1][nt], 0, 0, 0);
    }
  }
#pragma unroll
  for (int rt = 0; rt < 2; ++rt)
#pragma unroll
    for (int nt = 0; nt < 8; ++nt) {
      const int col = nt * 16 + l15;
      const float bcol = bias[col];
#pragma unroll
      for (int reg = 0; reg < 4; ++reg) {
        int row = row_base + rt * 16 + quad * 4 + reg;
        if (row < M) {
          float v = acc[rt][nt][reg] + bcol;
          v = (v >= 0.f) ? v : NEG * v;
          C[(size_t)row * D + col] = f2bf(v);
        }
      }
    }
}

// ---------------- fused GEMM: A -> (hq, hk) bf16 and out (+)= A@Wro + bro ----------------
// A fragments held in registers; Wq/Wk/Wro staged sequentially through one LDS buffer.
template <bool DO_QK, bool ACCUM>
__global__ __launch_bounds__(256) void gemm_qkro(const unsigned short* __restrict__ A,
                                                 const unsigned short* __restrict__ WTq,
                                                 const float* __restrict__ bq,
                                                 const unsigned short* __restrict__ WTk,
                                                 const float* __restrict__ bk,
                                                 const unsigned short* __restrict__ WTro,
                                                 const float* __restrict__ bro,
                                                 unsigned short* __restrict__ hq,
                                                 unsigned short* __restrict__ hk,
                                                 float* __restrict__ out, int M) {
  __shared__ unsigned short w[D * KP];
  const int t = threadIdx.x;
  const int wave = t >> 6;
  const int lane = t & 63;
  const int l15 = lane & 15;
  const int quad = lane >> 4;
  const int row_base = blockIdx.x * 128 + wave * 32;

  int r0 = row_base + l15;      if (r0 >= M) r0 = M - 1;
  int r1 = row_base + 16 + l15; if (r1 >= M) r1 = M - 1;
  const unsigned short* A0 = A + (size_t)r0 * D + quad * 8;
  const unsigned short* A1 = A + (size_t)r1 * D + quad * 8;
  bf8_t afr[2][4];
#pragma unroll
  for (int kc = 0; kc < 4; ++kc) {
    afr[0][kc] = *(const bf8_t*)(A0 + kc * 32);
    afr[1][kc] = *(const bf8_t*)(A1 + kc * 32);
  }

  auto stage = [&](const unsigned short* Wp) {
#pragma unroll
    for (int i = 0; i < 8; ++i) {
      int idx8 = t + i * 256;
      int n = idx8 >> 4, k8 = (idx8 & 15) << 3;
      *(uint4*)(&w[n * KP + k8]) = *(const uint4*)(&Wp[n * D + k8]);
    }
  };

  f4_t acc[2][8];
  auto compute = [&]() {
#pragma unroll
    for (int rt = 0; rt < 2; ++rt)
#pragma unroll
      for (int nt = 0; nt < 8; ++nt) acc[rt][nt] = (f4_t){0.f, 0.f, 0.f, 0.f};
#pragma unroll
    for (int kc = 0; kc < 4; ++kc) {
#pragma unroll
      for (int nt = 0; nt < 8; ++nt) {
        bf8_t b = *(const bf8_t*)(&w[(nt * 16 + l15) * KP + kc * 32 + quad * 8]);
        acc[0][nt] = __builtin_amdgcn_mfma_f32_16x16x32_bf16(afr[0][kc], b, acc[0][nt], 0, 0, 0);
        acc[1][nt] = __builtin_amdgcn_mfma_f32_16x16x32_bf16(afr[1][kc], b, acc[1][nt], 0, 0, 0);
      }
    }
  };

  auto store_bf = [&](const float* bias, unsigned short* C) {
#pragma unroll
    for (int rt = 0; rt < 2; ++rt)
#pragma unroll
      for (int nt = 0; nt < 8; ++nt) {
        const int col = nt * 16 + l15;
        const float bcol = bias[col];
#pragma unroll
        for (int reg = 0; reg < 4; ++reg) {
          int row = row_base + rt * 16 + quad * 4 + reg;
          if (row < M) C[(size_t)row * D + col] = f2bf(acc[rt][nt][reg] + bcol);
        }
      }
  };

  if (DO_QK) {
    stage(WTq);
    __syncthreads();
    compute();
    store_bf(bq, hq);
    __syncthreads();
    stage(WTk);
    __syncthreads();
    compute();
    store_bf(bk, hk);
    __syncthreads();
  }
  stage(WTro);
  __syncthreads();
  compute();
#pragma unroll
  for (int rt = 0; rt < 2; ++rt)
#pragma unroll
    for (int nt = 0; nt < 8; ++nt) {
      const int col = nt * 16 + l15;
      const float bcol = bro[col];
#pragma unroll
      for (int reg = 0; reg < 4; ++reg) {
        int row = row_base + rt * 16 + quad * 4 + reg;
        if (row < M) {
          float v = acc[rt][nt][reg] + bcol;
          float* Cp = out + (size_t)row * D + col;
          if (ACCUM) v += *Cp;
          *Cp = v;
        }
      }
    }
}

// ---------------- launch ----------------
extern "C" void kernel_launch(void* const* d_in, const int* in_sizes, int n_in,
                              void* d_out, int out_size, void* d_ws, size_t ws_size,
                              hipStream_t stream) {
  const float* feats = (const float*)d_in[0];
  const float* Wq = (const float*)d_in[1];
  const float* bq = (const float*)d_in[2];
  const float* Wk = (const float*)d_in[3];
  const float* bk = (const float*)d_in[4];
  const float* Wr = (const float*)d_in[5];
  const float* br = (const float*)d_in[6];
  const float* Wro = (const float*)d_in[7];
  const float* bro = (const float*)d_in[8];
  const int* src = (const int*)d_in[9];
  const int* dst = (const int*)d_in[10];
  float* out = (float*)d_out;

  size_t off = 0;
  char* base = (char*)d_ws;
  auto alloc = [&](size_t bytes) -> void* {
    void* p = base + off;
    off += (bytes + 255) & ~(size_t)255;
    return p;
  };
  int* bcnt = (int*)alloc((size_t)NBKT * 4);
  int* bfill = (int*)alloc((size_t)NBKT * 4);
  int* bptr = (int*)alloc((size_t)(NBKT + 1) * 4);
  int* ebuf = (int*)alloc((size_t)NE * 4);
  int* ssrc = (int*)alloc((size_t)NE * 4);
  int* rowptr = (int*)alloc((size_t)(NN + 1) * 4);
  int* deg = (int*)alloc((size_t)NN * 4);
  unsigned short* WT = (unsigned short*)alloc((size_t)9 * D * D * 2);
  unsigned short* x0 = (unsigned short*)alloc((size_t)NN * D * 2);
  unsigned short* hq = (unsigned short*)alloc((size_t)NN * D * 2);
  unsigned short* hk = (unsigned short*)alloc((size_t)NN * D * 2);
  unsigned short* ag = (unsigned short*)alloc((size_t)NN * D * 2);
  unsigned short* h = (unsigned short*)alloc((size_t)NN * D * 2);

  hipMemsetAsync(bcnt, 0, (size_t)NBKT * 4, stream);
  hipMemsetAsync(bfill, 0, (size_t)NBKT * 4, stream);

  prep_weights<<<dim3(64, 9), 256, 0, stream>>>(Wq, Wk, Wr, Wro, WT);
  convert_feats<<<(NN * D / 4 + 255) / 256, 256, 0, stream>>>(feats, x0);

  const int eb = (NE + 255) / 256;
  bucket_hist<<<eb, 256, 0, stream>>>(dst, bcnt);
  bucket_scan<<<1, 1024, 0, stream>>>(bcnt, bptr);
  bucket_scatter<<<eb, 256, 0, stream>>>(src, dst, bptr, bfill, ebuf);
  bucket_sort<<<NBKT, 256, 0, stream>>>(bptr, ebuf, ssrc, rowptr, deg);

  const int gb = (NN + 127) / 128;
  const int ab = (NN + 3) / 4;
  const size_t WM = (size_t)D * D;

  // F1: x0 -> hq0, hk0, out = x0@Wro0 + bro0
  gemm_qkro<true, false><<<gb, 256, 0, stream>>>(x0, WT + 0 * WM, bq, WT + 2 * WM, bk,
                                                 WT + 6 * WM, bro, hq, hk, out, NN);
  aggregate_kernel<<<ab, 256, 0, stream>>>(rowptr, ssrc, hq, hk, deg, ag);
  gemm_r<<<gb, 256, 0, stream>>>(ag, WT + 4 * WM, br, h, NN);

  // F3: h1 -> hq1, hk1, out += h1@Wro1 + bro1
  gemm_qkro<true, true><<<gb, 256, 0, stream>>>(h, WT + 1 * WM, bq + D, WT + 3 * WM, bk + D,
                                                WT + 7 * WM, bro + D, hq, hk, out, NN);
  aggregate_kernel<<<ab, 256, 0, stream>>>(rowptr, ssrc, hq, hk, deg, ag);
  gemm_r<<<gb, 256, 0, stream>>>(ag, WT + 5 * WM, br + D, h, NN);

  // F5: out += h2@Wro2 + bro2
  gemm_qkro<false, true><<<gb, 256, 0, stream>>>(h, nullptr, nullptr, nullptr, nullptr,
                                                 WT + 8 * WM, bro + 2 * D, nullptr, nullptr,
                                                 out, NN);
}

// Round 4
// 353.186 us; speedup vs baseline: 1.3110x; 1.3110x over previous
//
#include <hip/hip_runtime.h>

#define NN 50000
#define NE 800000
#define D 128
#define NEG 0.2f
#define KP 136           // padded LDS k-stride (bf16 elems)

#define NBLK1 256        // pass-1 blocks
#define TILE1 3125       // NE / NBLK1 (exact)
#define NB2 196          // ceil(NN/256) coarse buckets (dst>>8)
#define CAP2 8192        // max edges per coarse bucket (avg 4096, std ~64)

typedef short bf8_t __attribute__((ext_vector_type(8)));   // 8 x bf16 (16 B)
typedef float f4_t __attribute__((ext_vector_type(4)));

__device__ __forceinline__ unsigned short f2bf(float f) {
  unsigned int u = __float_as_uint(f);
  unsigned int r = (u + 0x7FFF + ((u >> 16) & 1)) >> 16;  // RNE
  return (unsigned short)r;
}
__device__ __forceinline__ float bf2f(unsigned int bits16) {
  return __uint_as_float(bits16 << 16);
}

// ---------------- weight prep: fp32 W[k][n] -> bf16 WT[n][k], 9 matrices ----------------
__global__ __launch_bounds__(256) void prep_weights(
    const float* __restrict__ Wq, const float* __restrict__ Wk,
    const float* __restrict__ Wr, const float* __restrict__ Wro,
    unsigned short* __restrict__ WT) {
  const int m = blockIdx.y;
  const float* src;
  if (m < 2) src = Wq + m * D * D;
  else if (m < 4) src = Wk + (m - 2) * D * D;
  else if (m < 6) src = Wr + (m - 4) * D * D;
  else src = Wro + (m - 6) * D * D;
  unsigned short* dstp = WT + m * D * D;
  const int t = threadIdx.x;
  const int n = blockIdx.x * 2 + (t >> 7);
  const int k = t & 127;
  dstp[n * D + k] = f2bf(src[k * D + n]);
}

__global__ __launch_bounds__(256) void convert_feats(const float* __restrict__ in,
                                                     unsigned short* __restrict__ out) {
  int i = (blockIdx.x * 256 + threadIdx.x) * 4;
  float4 v = *(const float4*)(in + i);
  ushort4 o = {f2bf(v.x), f2bf(v.y), f2bf(v.z), f2bf(v.w)};
  *(ushort4*)(out + i) = o;
}

// ---------------- CSR build: MSD counting sort, zero global atomics ----------------

// P1 hist: per-block LDS histogram of dst>>8; H[bin*NBLK1 + blk]
__global__ __launch_bounds__(256) void p1_hist(const int* __restrict__ dst,
                                               int* __restrict__ H) {
  __shared__ int cnt[NB2];
  const int t = threadIdx.x;
  const int blk = blockIdx.x;
  if (t < NB2) cnt[t] = 0;
  __syncthreads();
  const int beg = blk * TILE1, end = beg + TILE1;
  for (int i = beg + t; i < end; i += 256) atomicAdd(&cnt[dst[i] >> 8], 1);
  __syncthreads();
  if (t < NB2) H[t * NBLK1 + blk] = cnt[t];
}

// scan A: bin totals -> exclusive binbase[NB2+1] (single block, 256 thr)
__global__ __launch_bounds__(256) void p1_scanA(const int* __restrict__ H,
                                                int* __restrict__ binbase) {
  __shared__ int bs[NB2];
  __shared__ int sd[256];
  const int t = threadIdx.x;
  const int wave = t >> 6, lane = t & 63;
  for (int bin = wave; bin < NB2; bin += 4) {
    const int* row = H + bin * NBLK1;
    int v = row[lane] + row[lane + 64] + row[lane + 128] + row[lane + 192];
    for (int off = 32; off; off >>= 1) v += __shfl_down(v, off, 64);
    if (lane == 0) bs[bin] = v;
  }
  __syncthreads();
  int x = (t < NB2) ? bs[t] : 0;
  sd[t] = x;
  __syncthreads();
  int acc = x;
  for (int off = 1; off < 256; off <<= 1) {
    int y = (t >= off) ? sd[t - off] : 0;
    __syncthreads();
    acc += y;
    sd[t] = acc;
    __syncthreads();
  }
  if (t < NB2) binbase[t] = acc - x;   // exclusive
  if (t == 0) binbase[NB2] = NE;
}

// scan C: per-bin exclusive scan over blocks + binbase -> gofs[bin*NBLK1+blk]
__global__ __launch_bounds__(256) void p1_scanC(const int* __restrict__ H,
                                                const int* __restrict__ binbase,
                                                int* __restrict__ gofs) {
  __shared__ int sd[256];
  const int bin = blockIdx.x;
  const int t = threadIdx.x;
  int x = H[bin * NBLK1 + t];
  sd[t] = x;
  __syncthreads();
  int acc = x;
  for (int off = 1; off < 256; off <<= 1) {
    int y = (t >= off) ? sd[t - off] : 0;
    __syncthreads();
    acc += y;
    sd[t] = acc;
    __syncthreads();
  }
  gofs[bin * NBLK1 + t] = binbase[bin] + (acc - x);
}

// P1 scatter: place packed edges into coarse-bucket-contiguous ebuf (LDS-atomic ranks only)
__global__ __launch_bounds__(256) void p1_scatter(const int* __restrict__ src,
                                                  const int* __restrict__ dst,
                                                  const int* __restrict__ gofs,
                                                  unsigned int* __restrict__ ebuf) {
  __shared__ int lofs[NB2];
  const int t = threadIdx.x;
  const int blk = blockIdx.x;
  if (t < NB2) lofs[t] = gofs[t * NBLK1 + blk];
  __syncthreads();
  const int beg = blk * TILE1, end = beg + TILE1;
  for (int i = beg + t; i < end; i += 256) {
    unsigned int d = (unsigned int)dst[i];
    int pos = atomicAdd(&lofs[d >> 8], 1);
    ebuf[pos] = (unsigned int)src[i] | (d << 16);
  }
}

// P2: per-coarse-bucket LDS counting sort by dst&255 -> ssrc, rowptr, deg
__global__ __launch_bounds__(256) void p2_sort(const int* __restrict__ binbase,
                                               const unsigned int* __restrict__ ebuf,
                                               int* __restrict__ ssrc,
                                               int* __restrict__ rowptr,
                                               int* __restrict__ deg) {
  __shared__ int cnt[256], fill[256], sd[256];
  __shared__ unsigned int sorted[CAP2];
  const int b = blockIdx.x;
  const int t = threadIdx.x;
  const int beg = binbase[b], end = binbase[b + 1];
  const int n = end - beg;
  cnt[t] = 0;
  __syncthreads();
  for (int i = beg + t; i < end; i += 256)
    atomicAdd(&cnt[(ebuf[i] >> 16) & 255], 1);
  __syncthreads();
  int x = cnt[t];
  sd[t] = x;
  __syncthreads();
  int acc = x;
  for (int off = 1; off < 256; off <<= 1) {
    int y = (t >= off) ? sd[t - off] : 0;
    __syncthreads();
    acc += y;
    sd[t] = acc;
    __syncthreads();
  }
  const int excl = acc - x;
  fill[t] = excl;
  __syncthreads();
  for (int i = beg + t; i < end; i += 256) {
    unsigned int p = ebuf[i];
    int pos = atomicAdd(&fill[(p >> 16) & 255], 1);
    if (pos < CAP2) sorted[pos] = p;
  }
  __syncthreads();
  for (int i = t; i < n; i += 256) ssrc[beg + i] = (int)(sorted[i] & 0xFFFFu);
  const int node = (b << 8) + t;
  if (node < NN) {
    rowptr[node] = beg + excl;
    deg[node] = x;
  }
  if (b == 0 && t == 0) rowptr[NN] = NE;
}

// ---------------- aggregation: agg[v] = mean_e leaky(hq[v] + hk[src[e]]) ----------------
__global__ __launch_bounds__(256) void aggregate_kernel(
    const int* __restrict__ rowptr, const int* __restrict__ ssrc,
    const unsigned short* __restrict__ hq, const unsigned short* __restrict__ hk,
    const int* __restrict__ deg, unsigned short* __restrict__ agg) {
  const int v = blockIdx.x * 4 + (threadIdx.x >> 6);
  if (v >= NN) return;
  const int lane = threadIdx.x & 63;
  const int beg = rowptr[v];
  const int end = rowptr[v + 1];
  unsigned int qb = *(const unsigned int*)(hq + (size_t)v * D + lane * 2);
  const float q0 = bf2f(qb & 0xFFFFu);
  const float q1 = bf2f(qb >> 16);
  float a0 = 0.f, a1 = 0.f;
  int e = beg;
  for (; e + 4 <= end; e += 4) {
    int s0 = ssrc[e], s1 = ssrc[e + 1], s2 = ssrc[e + 2], s3 = ssrc[e + 3];
    unsigned int k0 = *(const unsigned int*)(hk + (size_t)s0 * D + lane * 2);
    unsigned int k1 = *(const unsigned int*)(hk + (size_t)s1 * D + lane * 2);
    unsigned int k2 = *(const unsigned int*)(hk + (size_t)s2 * D + lane * 2);
    unsigned int k3 = *(const unsigned int*)(hk + (size_t)s3 * D + lane * 2);
    float m;
    m = q0 + bf2f(k0 & 0xFFFFu); a0 += (m >= 0.f) ? m : NEG * m;
    m = q1 + bf2f(k0 >> 16);     a1 += (m >= 0.f) ? m : NEG * m;
    m = q0 + bf2f(k1 & 0xFFFFu); a0 += (m >= 0.f) ? m : NEG * m;
    m = q1 + bf2f(k1 >> 16);     a1 += (m >= 0.f) ? m : NEG * m;
    m = q0 + bf2f(k2 & 0xFFFFu); a0 += (m >= 0.f) ? m : NEG * m;
    m = q1 + bf2f(k2 >> 16);     a1 += (m >= 0.f) ? m : NEG * m;
    m = q0 + bf2f(k3 & 0xFFFFu); a0 += (m >= 0.f) ? m : NEG * m;
    m = q1 + bf2f(k3 >> 16);     a1 += (m >= 0.f) ? m : NEG * m;
  }
  for (; e < end; ++e) {
    int s = ssrc[e];
    unsigned int kb = *(const unsigned int*)(hk + (size_t)s * D + lane * 2);
    float m;
    m = q0 + bf2f(kb & 0xFFFFu); a0 += (m >= 0.f) ? m : NEG * m;
    m = q1 + bf2f(kb >> 16);     a1 += (m >= 0.f) ? m : NEG * m;
  }
  float dnm = fmaxf((float)deg[v], 1.f);
  unsigned int ob = (unsigned int)f2bf(a0 / dnm) | ((unsigned int)f2bf(a1 / dnm) << 16);
  *(unsigned int*)(agg + (size_t)v * D + lane * 2) = ob;
}

// ---------------- single-output MFMA GEMM (r-gemm: leaky, bf16 out) ----------------
__global__ __launch_bounds__(256) void gemm_r(const unsigned short* __restrict__ A,
                                              const unsigned short* __restrict__ WT,
                                              const float* __restrict__ bias,
                                              unsigned short* __restrict__ C, int M) {
  __shared__ unsigned short w[D * KP];
  const int t = threadIdx.x;
#pragma unroll
  for (int i = 0; i < 8; ++i) {
    int idx8 = t + i * 256;
    int n = idx8 >> 4, k8 = (idx8 & 15) << 3;
    *(uint4*)(&w[n * KP + k8]) = *(const uint4*)(&WT[n * D + k8]);
  }
  __syncthreads();

  const int wave = t >> 6;
  const int lane = t & 63;
  const int l15 = lane & 15;
  const int quad = lane >> 4;
  const int row_base = blockIdx.x * 128 + wave * 32;

  int r0 = row_base + l15;      if (r0 >= M) r0 = M - 1;
  int r1 = row_base + 16 + l15; if (r1 >= M) r1 = M - 1;
  const unsigned short* A0 = A + (size_t)r0 * D + quad * 8;
  const unsigned short* A1 = A + (size_t)r1 * D + quad * 8;

  f4_t acc[2][8] = {};
#pragma unroll
  for (int kc = 0; kc < 4; ++kc) {
    bf8_t a0 = *(const bf8_t*)(A0 + kc * 32);
    bf8_t a1 = *(const bf8_t*)(A1 + kc * 32);
#pragma unroll
    for (int nt = 0; nt < 8; ++nt) {
      bf8_t b = *(const bf8_t*)(&w[(nt * 16 + l15) * KP + kc * 32 + quad * 8]);
      acc[0][nt] = __builtin_amdgcn_mfma_f32_16x16x32_bf16(a0, b, acc[0][nt], 0, 0, 0);
      acc[1][nt] = __builtin_amdgcn_mfma_f32_16x16x32_bf16(a1, b, acc[1][nt], 0, 0, 0);
    }
  }
#pragma unroll
  for (int rt = 0; rt < 2; ++rt)
#pragma unroll
    for (int nt = 0; nt < 8; ++nt) {
      const int col = nt * 16 + l15;
      const float bcol = bias[col];
#pragma unroll
      for (int reg = 0; reg < 4; ++reg) {
        int row = row_base + rt * 16 + quad * 4 + reg;
        if (row < M) {
          float v = acc[rt][nt][reg] + bcol;
          v = (v >= 0.f) ? v : NEG * v;
          C[(size_t)row * D + col] = f2bf(v);
        }
      }
    }
}

// ---------------- fused GEMM: A -> (hq, hk) bf16 and out (+)= A@Wro + bro ----------------
template <bool DO_QK, bool ACCUM>
__global__ __launch_bounds__(256) void gemm_qkro(const unsigned short* __restrict__ A,
                                                 const unsigned short* __restrict__ WTq,
                                                 const float* __restrict__ bq,
                                                 const unsigned short* __restrict__ WTk,
                                                 const float* __restrict__ bk,
                                                 const unsigned short* __restrict__ WTro,
                                                 const float* __restrict__ bro,
                                                 unsigned short* __restrict__ hq,
                                                 unsigned short* __restrict__ hk,
                                                 float* __restrict__ out, int M) {
  __shared__ unsigned short w[D * KP];
  const int t = threadIdx.x;
  const int wave = t >> 6;
  const int lane = t & 63;
  const int l15 = lane & 15;
  const int quad = lane >> 4;
  const int row_base = blockIdx.x * 128 + wave * 32;

  int r0 = row_base + l15;      if (r0 >= M) r0 = M - 1;
  int r1 = row_base + 16 + l15; if (r1 >= M) r1 = M - 1;
  const unsigned short* A0 = A + (size_t)r0 * D + quad * 8;
  const unsigned short* A1 = A + (size_t)r1 * D + quad * 8;
  bf8_t afr[2][4];
#pragma unroll
  for (int kc = 0; kc < 4; ++kc) {
    afr[0][kc] = *(const bf8_t*)(A0 + kc * 32);
    afr[1][kc] = *(const bf8_t*)(A1 + kc * 32);
  }

  auto stage = [&](const unsigned short* Wp) {
#pragma unroll
    for (int i = 0; i < 8; ++i) {
      int idx8 = t + i * 256;
      int n = idx8 >> 4, k8 = (idx8 & 15) << 3;
      *(uint4*)(&w[n * KP + k8]) = *(const uint4*)(&Wp[n * D + k8]);
    }
  };

  f4_t acc[2][8];
  auto compute = [&]() {
#pragma unroll
    for (int rt = 0; rt < 2; ++rt)
#pragma unroll
      for (int nt = 0; nt < 8; ++nt) acc[rt][nt] = (f4_t){0.f, 0.f, 0.f, 0.f};
#pragma unroll
    for (int kc = 0; kc < 4; ++kc) {
#pragma unroll
      for (int nt = 0; nt < 8; ++nt) {
        bf8_t b = *(const bf8_t*)(&w[(nt * 16 + l15) * KP + kc * 32 + quad * 8]);
        acc[0][nt] = __builtin_amdgcn_mfma_f32_16x16x32_bf16(afr[0][kc], b, acc[0][nt], 0, 0, 0);
        acc[1][nt] = __builtin_amdgcn_mfma_f32_16x16x32_bf16(afr[1][kc], b, acc[1][nt], 0, 0, 0);
      }
    }
  };

  auto store_bf = [&](const float* bias, unsigned short* C) {
#pragma unroll
    for (int rt = 0; rt < 2; ++rt)
#pragma unroll
      for (int nt = 0; nt < 8; ++nt) {
        const int col = nt * 16 + l15;
        const float bcol = bias[col];
#pragma unroll
        for (int reg = 0; reg < 4; ++reg) {
          int row = row_base + rt * 16 + quad * 4 + reg;
          if (row < M) C[(size_t)row * D + col] = f2bf(acc[rt][nt][reg] + bcol);
        }
      }
  };

  if (DO_QK) {
    stage(WTq);
    __syncthreads();
    compute();
    store_bf(bq, hq);
    __syncthreads();
    stage(WTk);
    __syncthreads();
    compute();
    store_bf(bk, hk);
    __syncthreads();
  }
  stage(WTro);
  __syncthreads();
  compute();
#pragma unroll
  for (int rt = 0; rt < 2; ++rt)
#pragma unroll
    for (int nt = 0; nt < 8; ++nt) {
      const int col = nt * 16 + l15;
      const float bcol = bro[col];
#pragma unroll
      for (int reg = 0; reg < 4; ++reg) {
        int row = row_base + rt * 16 + quad * 4 + reg;
        if (row < M) {
          float v = acc[rt][nt][reg] + bcol;
          float* Cp = out + (size_t)row * D + col;
          if (ACCUM) v += *Cp;
          *Cp = v;
        }
      }
    }
}

// ---------------- launch ----------------
extern "C" void kernel_launch(void* const* d_in, const int* in_sizes, int n_in,
                              void* d_out, int out_size, void* d_ws, size_t ws_size,
                              hipStream_t stream) {
  const float* feats = (const float*)d_in[0];
  const float* Wq = (const float*)d_in[1];
  const float* bq = (const float*)d_in[2];
  const float* Wk = (const float*)d_in[3];
  const float* bk = (const float*)d_in[4];
  const float* Wr = (const float*)d_in[5];
  const float* br = (const float*)d_in[6];
  const float* Wro = (const float*)d_in[7];
  const float* bro = (const float*)d_in[8];
  const int* src = (const int*)d_in[9];
  const int* dst = (const int*)d_in[10];
  float* out = (float*)d_out;

  size_t off = 0;
  char* base = (char*)d_ws;
  auto alloc = [&](size_t bytes) -> void* {
    void* p = base + off;
    off += (bytes + 255) & ~(size_t)255;
    return p;
  };
  int* H = (int*)alloc((size_t)NB2 * NBLK1 * 4);
  int* gofs = (int*)alloc((size_t)NB2 * NBLK1 * 4);
  int* binbase = (int*)alloc((size_t)(NB2 + 1) * 4);
  unsigned int* ebuf = (unsigned int*)alloc((size_t)NE * 4);
  int* ssrc = (int*)alloc((size_t)NE * 4);
  int* rowptr = (int*)alloc((size_t)(NN + 1) * 4);
  int* deg = (int*)alloc((size_t)NN * 4);
  unsigned short* WT = (unsigned short*)alloc((size_t)9 * D * D * 2);
  unsigned short* x0 = (unsigned short*)alloc((size_t)NN * D * 2);
  unsigned short* hq = (unsigned short*)alloc((size_t)NN * D * 2);
  unsigned short* hk = (unsigned short*)alloc((size_t)NN * D * 2);
  unsigned short* ag = (unsigned short*)alloc((size_t)NN * D * 2);
  unsigned short* h = (unsigned short*)alloc((size_t)NN * D * 2);

  prep_weights<<<dim3(64, 9), 256, 0, stream>>>(Wq, Wk, Wr, Wro, WT);
  convert_feats<<<(NN * D / 4 + 255) / 256, 256, 0, stream>>>(feats, x0);

  p1_hist<<<NBLK1, 256, 0, stream>>>(dst, H);
  p1_scanA<<<1, 256, 0, stream>>>(H, binbase);
  p1_scanC<<<NB2, 256, 0, stream>>>(H, binbase, gofs);
  p1_scatter<<<NBLK1, 256, 0, stream>>>(src, dst, gofs, ebuf);
  p2_sort<<<NB2, 256, 0, stream>>>(binbase, ebuf, ssrc, rowptr, deg);

  const int gb = (NN + 127) / 128;
  const int ab = (NN + 3) / 4;
  const size_t WM = (size_t)D * D;

  // F1: x0 -> hq0, hk0, out = x0@Wro0 + bro0
  gemm_qkro<true, false><<<gb, 256, 0, stream>>>(x0, WT + 0 * WM, bq, WT + 2 * WM, bk,
                                                 WT + 6 * WM, bro, hq, hk, out, NN);
  aggregate_kernel<<<ab, 256, 0, stream>>>(rowptr, ssrc, hq, hk, deg, ag);
  gemm_r<<<gb, 256, 0, stream>>>(ag, WT + 4 * WM, br, h, NN);

  // F3: h1 -> hq1, hk1, out += h1@Wro1 + bro1
  gemm_qkro<true, true><<<gb, 256, 0, stream>>>(h, WT + 1 * WM, bq + D, WT + 3 * WM, bk + D,
                                                WT + 7 * WM, bro + D, hq, hk, out, NN);
  aggregate_kernel<<<ab, 256, 0, stream>>>(rowptr, ssrc, hq, hk, deg, ag);
  gemm_r<<<gb, 256, 0, stream>>>(ag, WT + 5 * WM, br + D, h, NN);

  // F5: out += h2@Wro2 + bro2
  gemm_qkro<false, true><<<gb, 256, 0, stream>>>(h, nullptr, nullptr, nullptr, nullptr,
                                                 WT + 8 * WM, bro + 2 * D, nullptr, nullptr,
                                                 out, NN);
}